// Round 5
// baseline (161.336 us; speedup 1.0000x reference)
//
#include <hip/hip_runtime.h>
#include <math.h>

#define F_IN 256
#define F_OUT 64
#define NEG_SLOPE 0.01f
#define CAP 8192          // fixed capacity per coarse bucket (mean 4096, sigma 64)
#define NB2 256           // scatter blocks

typedef unsigned short ushort8_t __attribute__((ext_vector_type(8)));
typedef __bf16 bf16x8 __attribute__((ext_vector_type(8)));
typedef float f32x16 __attribute__((ext_vector_type(16)));

__device__ inline unsigned short f2bf(float f) {   // RNE
    unsigned u = __float_as_uint(f);
    u += 0x7FFF + ((u >> 16) & 1);
    return (unsigned short)(u >> 16);
}
__device__ inline float bf2f(unsigned short u) {
    return __uint_as_float(((unsigned)u) << 16);
}
// fp32 -> bf16 hi + bf16 lo (hi+lo ~ 2^-17 rel accurate)
__device__ inline void splitbf(float x, unsigned short& hi, unsigned short& lo) {
    hi = f2bf(x);
    lo = f2bf(x - bf2f(hi));
}
__device__ inline bf16x8 asbf8(ushort8_t u) {
    union { ushort8_t u; bf16x8 b; } c; c.u = u; return c.b;
}
__device__ inline void split8u(const float4& p0, const float4& p1, ushort8_t& h, ushort8_t& l) {
    unsigned short th, tl;
    splitbf(p0.x, th, tl); h[0] = th; l[0] = tl;
    splitbf(p0.y, th, tl); h[1] = th; l[1] = tl;
    splitbf(p0.z, th, tl); h[2] = th; l[2] = tl;
    splitbf(p0.w, th, tl); h[3] = th; l[3] = tl;
    splitbf(p1.x, th, tl); h[4] = th; l[4] = tl;
    splitbf(p1.y, th, tl); h[5] = th; l[5] = tl;
    splitbf(p1.z, th, tl); h[6] = th; l[6] = tl;
    splitbf(p1.w, th, tl); h[7] = th; l[7] = tl;
}
__device__ inline float redq32(float v) {   // sum over the 32 lanes of a q-half
    v += __shfl_xor(v, 1);  v += __shfl_xor(v, 2);  v += __shfl_xor(v, 4);
    v += __shfl_xor(v, 8);  v += __shfl_xor(v, 16);
    return v;
}

// ---------------------------------------------------------------------------
// L1: prep-frag (blocks 0..15) UNION x-transform (blocks 16..16+NTT-1)
// UNION scatter (last NB2 blocks). All three touch disjoint data, no sync.
//
// prep: build MFMA B-fragments of W1, W2 as bf16 hi/lo pairs.
// 32x32x16 B layout: B[k][n]: n = lane&31, k = (lane>>5)*8 + j.
//
// transform (R11): pre-split x into MFMA A-fragments xfh/xfl so the mlp
// k-loop reads are 100% coalesced. R10 lesson: lane-per-row x loads in mlp
// expand to ~32-64 cache lines per instr -> 50us latency-bound dispatch.
// Here the scatter is on the READ side of a pure streaming kernel (full
// occupancy, TLP hides it); writes are exactly linear per-thread ushort8.
// Block = one 32-node tile; wave = one kstep (gks = tid>>6).
// xf layout == w1 frag layout per tile: ((t*16+gks)*64 + lane)*8 + j,
// covering row = t*32 + (lane&31) (clamped), k = gks*16 + (lane>>5)*8 + j.
//
// scatter: per-block LDS hist of dst>>8, ONE global atomicAdd per
// (block,bucket) reserves a sub-range in the bucket's fixed-CAP region,
// then LDS-cursor scatter. No per-edge global atomics.
// ---------------------------------------------------------------------------
__global__ __launch_bounds__(1024)
void prep_scatter_kernel(const float* __restrict__ W1, const float* __restrict__ W2,
                         unsigned short* __restrict__ w1fh, unsigned short* __restrict__ w1fl,
                         unsigned short* __restrict__ w2fh, unsigned short* __restrict__ w2fl,
                         const float* __restrict__ x,
                         unsigned short* __restrict__ xfh, unsigned short* __restrict__ xfl,
                         int NTT, int N,
                         const int* __restrict__ src, const int* __restrict__ dst,
                         int* __restrict__ cursor, int* __restrict__ edata,
                         int E, int chunk)
{
    __shared__ int lh[256], lbase[256], lcur[256];
    const int tid = threadIdx.x;

    if (blockIdx.x < 16) {   // ---- prep half ----
        int idx = blockIdx.x * 1024 + tid;   // 0..16383
        int jj = idx & 7, l = (idx >> 3) & 63, t = idx >> 9;
        {
            int nt = t & 1, gks = t >> 1;
            int f = nt * 32 + (l & 31);
            int k = gks * 16 + (l >> 5) * 8 + jj;
            unsigned short hi, lo;
            splitbf(W1[f * F_IN + k], hi, lo);
            w1fh[idx] = hi; w1fl[idx] = lo;
        }
        if (idx < 4096) {
            int nt = t & 1, ks = t >> 1;   // t 0..7
            int f = nt * 32 + (l & 31);
            int j = ks * 16 + (l >> 5) * 8 + jj;
            unsigned short hi, lo;
            splitbf(W2[f * F_OUT + j], hi, lo);
            w2fh[idx] = hi; w2fl[idx] = lo;
        }
        return;
    }

    if (blockIdx.x < 16 + NTT) {   // ---- x transform ----
        const int t = blockIdx.x - 16;
        const int gks = tid >> 6, lane = tid & 63;
        const int ml = lane & 31, q = lane >> 5;
        const int row = min(t * 32 + ml, N - 1);
        const float* xr = x + (size_t)row * F_IN + gks * 16 + q * 8;
        float4 p0 = *(const float4*)xr;
        float4 p1 = *(const float4*)(xr + 4);
        ushort8_t h, l;
        split8u(p0, p1, h, l);
        size_t off = ((size_t)t * 1024 + tid) * 8;
        *(ushort8_t*)(xfh + off) = h;
        *(ushort8_t*)(xfl + off) = l;
        return;
    }

    // ---- scatter half ----
    const int bid = blockIdx.x - 16 - NTT;
    if (tid < 256) lh[tid] = 0;
    __syncthreads();
    const int beg = bid * chunk;
    const int end = min(E, beg + chunk);
    for (int i = beg + tid; i < end; i += 1024)
        atomicAdd(&lh[((unsigned)dst[i]) >> 8], 1);
    __syncthreads();
    if (tid < 256) {
        int c = lh[tid];
        lbase[tid] = c ? atomicAdd(&cursor[tid], c) : 0;
        lcur[tid] = 0;
    }
    __syncthreads();
    for (int i = beg + tid; i < end; i += 1024) {
        int d = dst[i];
        int s = src[i];
        int b = ((unsigned)d) >> 8;
        int rk = atomicAdd(&lcur[b], 1);
        edata[b * CAP + lbase[b] + rk] = ((d & 0xFF) << 16) | s;
    }
}

// ---------------------------------------------------------------------------
// L2: mlp (blocks 0..MLPB-1) UNION bucket_sort (blocks MLPB..MLPB+nbc-1).
//
// mlp (R11): all GEMM1 operands are pre-staged fragments -> every load in
// the k-loop is a coalesced 16B/lane read (1KB per wave-instr). Zero VALU
// in the k-loop (split8 moved to the L1 transform). Plain unrolled loop;
// launch_bounds(256,2) relaxes VGPR cap (grid-limited occupancy anyway)
// so the compiler can pipeline loads deep. One wave owns 32 nodes x 64
// feats; per-wave-private LDS z transpose for GEMM2; scores via
// in-register 32-lane xor-tree.
//
// sort: fine counting sort within each coarse bucket (stride 256).
// ---------------------------------------------------------------------------
__global__ __launch_bounds__(256, 2)
void mlp_sort_kernel(const unsigned short* __restrict__ xfh,
                     const unsigned short* __restrict__ xfl,
                     const unsigned short* __restrict__ w1fh,
                     const unsigned short* __restrict__ w1fl,
                     const unsigned short* __restrict__ w2fh,
                     const unsigned short* __restrict__ w2fl,
                     const float* __restrict__ a,
                     unsigned short* __restrict__ hb,
                     float* __restrict__ sdst,
                     float* __restrict__ ssrc, int N,
                     const int* __restrict__ cursor,
                     const int* __restrict__ edata,
                     int* __restrict__ ssorted,
                     int* __restrict__ cnt, int* __restrict__ offs,
                     int MLPB)
{
    // mlp: per-wave z scratch zh[32][66]+zl[32][66] ushorts (odd dw stride ->
    // conflict-free b128 reads). 4 waves x 8448B = 33.8KB.
    __shared__ __align__(16) unsigned short zbuf[4 * 4224];
    __shared__ int hist[256];
    __shared__ int excl[256];

    const int tid = threadIdx.x;
    const int lane = tid & 63;

    if (blockIdx.x < MLPB) {   // ---- mlp half ----
        const int wid = __builtin_amdgcn_readfirstlane(tid >> 6);
        const int ml = lane & 31;          // node index within wave tile
        const int q = lane >> 5;           // K-octet selector
        const int node0w = blockIdx.x * 128 + wid * 32;
        const int t = blockIdx.x * 4 + wid;

        unsigned short* zh = zbuf + wid * 4224;
        unsigned short* zl = zh + 2112;

        const unsigned short* __restrict__ xbh = xfh + (size_t)t * 8192;
        const unsigned short* __restrict__ xbl = xfl + (size_t)t * 8192;

        f32x16 acc0, acc1;
#pragma unroll
        for (int i = 0; i < 16; i++) { acc0[i] = 0.f; acc1[i] = 0.f; }

        // ---- GEMM1: z = relu(x @ W1^T), K=256 as 16 MFMA k-steps.
        // 6 coalesced 16B loads + 6 MFMAs per kstep, no VALU. ----
#pragma unroll
        for (int gks = 0; gks < 16; gks++) {
            bf16x8 ah = asbf8(*(const ushort8_t*)(xbh + gks * 512 + lane * 8));
            bf16x8 al = asbf8(*(const ushort8_t*)(xbl + gks * 512 + lane * 8));
            bf16x8 bh0 = asbf8(*(const ushort8_t*)(w1fh + ((gks * 2 + 0) * 64 + lane) * 8));
            bf16x8 bl0 = asbf8(*(const ushort8_t*)(w1fl + ((gks * 2 + 0) * 64 + lane) * 8));
            bf16x8 bh1 = asbf8(*(const ushort8_t*)(w1fh + ((gks * 2 + 1) * 64 + lane) * 8));
            bf16x8 bl1 = asbf8(*(const ushort8_t*)(w1fl + ((gks * 2 + 1) * 64 + lane) * 8));
            acc0 = __builtin_amdgcn_mfma_f32_32x32x16_bf16(ah, bh0, acc0, 0, 0, 0);
            acc0 = __builtin_amdgcn_mfma_f32_32x32x16_bf16(ah, bl0, acc0, 0, 0, 0);
            acc0 = __builtin_amdgcn_mfma_f32_32x32x16_bf16(al, bh0, acc0, 0, 0, 0);
            acc1 = __builtin_amdgcn_mfma_f32_32x32x16_bf16(ah, bh1, acc1, 0, 0, 0);
            acc1 = __builtin_amdgcn_mfma_f32_32x32x16_bf16(ah, bl1, acc1, 0, 0, 0);
            acc1 = __builtin_amdgcn_mfma_f32_32x32x16_bf16(al, bh1, acc1, 0, 0, 0);
        }

        // ---- z -> per-wave LDS (hi/lo), C layout: col(feat)=lane&31,
        // row(node) = (reg&3)+8*(reg>>2)+4*q ----
#pragma unroll
        for (int reg = 0; reg < 16; reg++) {
            int nd = (reg & 3) + 8 * (reg >> 2) + 4 * q;
            float z0 = fmaxf(acc0[reg], 0.f);
            float z1 = fmaxf(acc1[reg], 0.f);
            unsigned short h_, l_;
            splitbf(z0, h_, l_);
            zh[nd * 66 + ml] = h_; zl[nd * 66 + ml] = l_;
            splitbf(z1, h_, l_);
            zh[nd * 66 + 32 + ml] = h_; zl[nd * 66 + 32 + ml] = l_;
        }
        // wave-private region: lgkmcnt orders the dependent ds_read.

        // ---- GEMM2: h = relu(z @ W2^T), K=64 as 4 MFMA k-steps ----
        f32x16 hacc0, hacc1;
#pragma unroll
        for (int i = 0; i < 16; i++) { hacc0[i] = 0.f; hacc1[i] = 0.f; }
#pragma unroll
        for (int ks = 0; ks < 4; ks++) {
            bf16x8 wh0 = asbf8(*(const ushort8_t*)(w2fh + ((ks * 2 + 0) * 64 + lane) * 8));
            bf16x8 wl0 = asbf8(*(const ushort8_t*)(w2fl + ((ks * 2 + 0) * 64 + lane) * 8));
            bf16x8 wh1 = asbf8(*(const ushort8_t*)(w2fh + ((ks * 2 + 1) * 64 + lane) * 8));
            bf16x8 wl1 = asbf8(*(const ushort8_t*)(w2fl + ((ks * 2 + 1) * 64 + lane) * 8));
            bf16x8 ah = asbf8(*(const ushort8_t*)(zh + ml * 66 + ks * 16 + q * 8));
            bf16x8 al = asbf8(*(const ushort8_t*)(zl + ml * 66 + ks * 16 + q * 8));
            hacc0 = __builtin_amdgcn_mfma_f32_32x32x16_bf16(ah, wh0, hacc0, 0, 0, 0);
            hacc0 = __builtin_amdgcn_mfma_f32_32x32x16_bf16(ah, wl0, hacc0, 0, 0, 0);
            hacc0 = __builtin_amdgcn_mfma_f32_32x32x16_bf16(al, wh0, hacc0, 0, 0, 0);
            hacc1 = __builtin_amdgcn_mfma_f32_32x32x16_bf16(ah, wh1, hacc1, 0, 0, 0);
            hacc1 = __builtin_amdgcn_mfma_f32_32x32x16_bf16(ah, wl1, hacc1, 0, 0, 0);
            hacc1 = __builtin_amdgcn_mfma_f32_32x32x16_bf16(al, wh1, hacc1, 0, 0, 0);
        }

        // ---- epilogue: scores via in-register xor-tree, hb from regs ----
        const float aD0 = a[ml],            aD1 = a[32 + ml];
        const float aS0 = a[F_OUT + ml],    aS1 = a[F_OUT + 32 + ml];

        float sdv = 0.f, ssv = 0.f;
#pragma unroll
        for (int reg = 0; reg < 16; reg++) {
            int nd = (reg & 3) + 8 * (reg >> 2) + 4 * q;
            float h0 = fmaxf(hacc0[reg], 0.f);
            float h1 = fmaxf(hacc1[reg], 0.f);
            float td = redq32(h0 * aD0 + h1 * aD1);
            float ts = redq32(h0 * aS0 + h1 * aS1);
            if (ml == nd) { sdv = td; ssv = ts; }
            int gn = node0w + nd;
            if (gn < N) {
                hb[(size_t)gn * F_OUT + ml]      = f2bf(h0);
                hb[(size_t)gn * F_OUT + 32 + ml] = f2bf(h1);
            }
        }
        {
            int gn = node0w + ml;
            if ((((ml >> 2) & 1) == q) && gn < N) {
                sdst[gn] = sdv;
                ssrc[gn] = ssv;
            }
        }
        return;
    }

    // ---- sort half ----
    const int cb = blockIdx.x - MLPB;
    const int base = cb * CAP;
    const int ecnt = cursor[cb];

    hist[tid] = 0;
    __syncthreads();
    for (int i = tid; i < ecnt; i += 256)
        atomicAdd(&hist[((unsigned)edata[base + i]) >> 16], 1);
    __syncthreads();

    if (tid < 64) {
        int v0 = hist[lane * 4], v1 = hist[lane * 4 + 1];
        int v2 = hist[lane * 4 + 2], v3 = hist[lane * 4 + 3];
        int ts = v0 + v1 + v2 + v3;
        int s = ts;
#pragma unroll
        for (int d = 1; d < 64; d <<= 1) {
            int t = __shfl_up(s, d);
            if (lane >= d) s += t;
        }
        int e = s - ts;
        excl[lane * 4] = e;
        excl[lane * 4 + 1] = e + v0;
        excl[lane * 4 + 2] = e + v0 + v1;
        excl[lane * 4 + 3] = e + v0 + v1 + v2;
    }
    __syncthreads();

    {
        int d = cb * 256 + tid;
        if (d < N) {
            cnt[d] = hist[tid];
            offs[d] = base + excl[tid];
        }
    }
    __syncthreads();

    for (int i = tid; i < ecnt; i += 256) {
        int pack = edata[base + i];
        int low = ((unsigned)pack) >> 16;
        int rk = atomicAdd(&excl[low], 1);
        ssorted[base + rk] = pack & 0xFFFF;
    }
}

// ---------------------------------------------------------------------------
// L3: per-dst-node online-softmax aggregation (R10 structure: 4 nodes per
// wave, 16-lane groups; ushort4 row gathers; float4 output).
// ---------------------------------------------------------------------------
__global__ __launch_bounds__(256)
void aggregate_kernel(const unsigned short* __restrict__ hb,
                      const float* __restrict__ sdst,
                      const float* __restrict__ ssrc,
                      const int* __restrict__ offs,
                      const int* __restrict__ cnt,
                      const int* __restrict__ ssorted,
                      float* __restrict__ out, int N)
{
    __shared__ float2 ws_sh[4][64];
    const int tid = threadIdx.x;
    const int lane = tid & 63;
    const int wid = tid >> 6;
    const int g = lane >> 4;          // node group within wave (0..3)
    const int li = lane & 15;         // lane within group
    const int d = blockIdx.x * 16 + wid * 4 + g;
    const bool vd = d < N;

    const int off = vd ? offs[d] : 0;
    const int deg = vd ? cnt[d] : 0;
    const float sdd = vd ? sdst[d] : 0.f;

    float M = -INFINITY, S = 0.f;
    float c0 = 0.f, c1 = 0.f, c2 = 0.f, c3 = 0.f;

    for (int cb = 0; cb < deg; cb += 16) {
        int ce = min(16, deg - cb);
        float score = -INFINITY;
        int s = 0;
        if (li < ce) {
            s = ssorted[off + cb + li];
            float sc = sdd + ssrc[s];
            score = sc > 0.f ? sc : NEG_SLOPE * sc;
        }
        float mc = score;
        mc = fmaxf(mc, __shfl_xor(mc, 1));
        mc = fmaxf(mc, __shfl_xor(mc, 2));
        mc = fmaxf(mc, __shfl_xor(mc, 4));
        mc = fmaxf(mc, __shfl_xor(mc, 8));
        float newM = fmaxf(M, mc);
        float scale = __expf(M - newM);
        float w = (li < ce) ? __expf(score - newM) : 0.f;
        ws_sh[wid][lane] = make_float2(w, __int_as_float(s));
        float csum = w;
        csum += __shfl_xor(csum, 1);
        csum += __shfl_xor(csum, 2);
        csum += __shfl_xor(csum, 4);
        csum += __shfl_xor(csum, 8);
        S = S * scale + csum;
        __builtin_amdgcn_wave_barrier();

        // gather: 16 edges (zero-weight padded), lane li covers feats 4li..4li+3
        float t0 = 0.f, t1 = 0.f, t2 = 0.f, t3 = 0.f;
#pragma unroll
        for (int e = 0; e < 16; e++) {
            float2 tw = ws_sh[wid][g * 16 + e];
            int se = __float_as_int(tw.y);
            ushort4 r = *(const ushort4*)(hb + (((size_t)(unsigned)se) << 6) + li * 4);
            t0 = fmaf(tw.x, bf2f(r.x), t0);
            t1 = fmaf(tw.x, bf2f(r.y), t1);
            t2 = fmaf(tw.x, bf2f(r.z), t2);
            t3 = fmaf(tw.x, bf2f(r.w), t3);
        }
        c0 = c0 * scale + t0;
        c1 = c1 * scale + t1;
        c2 = c2 * scale + t2;
        c3 = c3 * scale + t3;
        __builtin_amdgcn_wave_barrier();
        M = newM;
    }

    if (vd) {
        ushort4 hr = *(const ushort4*)(hb + (((size_t)(unsigned)d) << 6) + li * 4);
        float inv = (S > 0.f) ? 1.f / S : 0.f;
        float r0 = bf2f(hr.x) - c0 * inv;
        float r1 = bf2f(hr.y) - c1 * inv;
        float r2 = bf2f(hr.z) - c2 * inv;
        float r3 = bf2f(hr.w) - c3 * inv;
        float4 o;
        o.x = r0 > 0.f ? r0 : 0.f;
        o.y = r1 > 0.f ? r1 : 0.f;
        o.z = r2 > 0.f ? r2 : 0.f;
        o.w = r3 > 0.f ? r3 : 0.f;
        *(float4*)(out + (size_t)d * F_OUT + li * 4) = o;
    }
}

// ---------------------------------------------------------------------------
extern "C" void kernel_launch(void* const* d_in, const int* in_sizes, int n_in,
                              void* d_out, int out_size, void* d_ws,
                              size_t ws_size, hipStream_t stream)
{
    const float* x  = (const float*)d_in[0];
    const float* W1 = (const float*)d_in[1];
    const float* W2 = (const float*)d_in[2];
    const float* a  = (const float*)d_in[3];
    const int* src  = (const int*)d_in[4];
    const int* dst  = (const int*)d_in[5];
    const int N = in_sizes[0] / F_IN;   // 50000
    const int E = in_sizes[4];          // 800000

    const int nbc = (N + 255) >> 8;                     // 196
    const int MLPB = (N + 127) >> 7;                    // 391
    const int NTT = MLPB * 4;                           // 1564 node-tiles
    const int chunk = (E + NB2 - 1) / NB2;

    float* ws = (float*)d_ws;
    float* sdst = ws;                                   // N
    float* ssrc = sdst + N;                             // N
    unsigned short* w1fh = (unsigned short*)(ssrc + N); // 16384 us
    unsigned short* w1fl = w1fh + 16384;                // 16384 us
    unsigned short* w2fh = w1fl + 16384;                // 4096 us
    unsigned short* w2fl = w2fh + 4096;                 // 4096 us
    unsigned short* xfh = w2fl + 4096;                  // NTT*8192 us
    unsigned short* xfl = xfh + (size_t)NTT * 8192;     // NTT*8192 us
    unsigned short* hb = xfl + (size_t)NTT * 8192;      // N*64 us
    int* cnt    = (int*)(hb + (size_t)N * F_OUT);       // N
    int* offs   = cnt + N;                              // N
    int* cursor = offs + N;                             // 256
    int* edata  = cursor + 256;                         // 196*CAP
    int* ssorted = edata + 196 * CAP;                   // 196*CAP

    hipMemsetAsync(cursor, 0, 256 * sizeof(int), stream);
    prep_scatter_kernel<<<16 + NTT + NB2, 1024, 0, stream>>>(
        W1, W2, w1fh, w1fl, w2fh, w2fl,
        x, xfh, xfl, NTT, N,
        src, dst, cursor, edata, E, chunk);
    mlp_sort_kernel<<<MLPB + nbc, 256, 0, stream>>>(xfh, xfl, w1fh, w1fl, w2fh, w2fl, a,
                                                    hb, sdst, ssrc, N,
                                                    cursor, edata, ssorted, cnt, offs,
                                                    MLPB);
    aggregate_kernel<<<(N + 15) / 16, 256, 0, stream>>>(hb, sdst, ssrc, offs, cnt,
                                                        ssorted, (float*)d_out, N);
}

// Round 6
// 147.884 us; speedup vs baseline: 1.0910x; 1.0910x over previous
//
#include <hip/hip_runtime.h>
#include <math.h>

#define F_IN 256
#define F_OUT 64
#define NEG_SLOPE 0.01f
#define CAP 8192          // fixed capacity per coarse bucket (mean 4096, sigma 64)
#define NB2 256           // scatter blocks

typedef unsigned short ushort8_t __attribute__((ext_vector_type(8)));
typedef __bf16 bf16x8 __attribute__((ext_vector_type(8)));
typedef float f32x16 __attribute__((ext_vector_type(16)));

__device__ inline unsigned short f2bf(float f) {   // RNE
    unsigned u = __float_as_uint(f);
    u += 0x7FFF + ((u >> 16) & 1);
    return (unsigned short)(u >> 16);
}
__device__ inline float bf2f(unsigned short u) {
    return __uint_as_float(((unsigned)u) << 16);
}
// fp32 -> bf16 hi + bf16 lo (hi+lo ~ 2^-17 rel accurate)
__device__ inline void splitbf(float x, unsigned short& hi, unsigned short& lo) {
    hi = f2bf(x);
    lo = f2bf(x - bf2f(hi));
}
__device__ inline bf16x8 asbf8(ushort8_t u) {
    union { ushort8_t u; bf16x8 b; } c; c.u = u; return c.b;
}
__device__ inline float redq32(float v) {   // sum over the 32 lanes of a q-half
    v += __shfl_xor(v, 1);  v += __shfl_xor(v, 2);  v += __shfl_xor(v, 4);
    v += __shfl_xor(v, 8);  v += __shfl_xor(v, 16);
    return v;
}

// ---------------------------------------------------------------------------
// L1: prep-frag (blocks 0..15) UNION scatter (blocks 16..271). Disjoint
// data, no cross-half sync. (R5's x->frag global pre-pass REVERTED: it
// added a 102MB HBM round-trip = +15us. Transform now happens through LDS
// inside mlp.)
//
// prep: build MFMA B-fragments of W1, W2 as bf16 hi/lo pairs.
// 32x32x16 B layout: B[k][n]: n = lane&31, k = (lane>>5)*8 + j.
// w1frag[((gks*2+nt)*64 + lane)*8 + j] covers f = nt*32+(lane&31),
// k = gks*16 + (lane>>5)*8 + j  (gks 0..15). w2frag same with K=64.
//
// scatter: per-block LDS hist of dst>>8, ONE global atomicAdd per
// (block,bucket) reserves a sub-range in the bucket's fixed-CAP region,
// then LDS-cursor scatter. No per-edge global atomics.
// ---------------------------------------------------------------------------
__global__ __launch_bounds__(1024)
void prep_scatter_kernel(const float* __restrict__ W1, const float* __restrict__ W2,
                         unsigned short* __restrict__ w1fh, unsigned short* __restrict__ w1fl,
                         unsigned short* __restrict__ w2fh, unsigned short* __restrict__ w2fl,
                         const int* __restrict__ src, const int* __restrict__ dst,
                         int* __restrict__ cursor, int* __restrict__ edata,
                         int E, int chunk)
{
    __shared__ int lh[256], lbase[256], lcur[256];
    const int tid = threadIdx.x;

    if (blockIdx.x < 16) {   // ---- prep half ----
        int idx = blockIdx.x * 1024 + tid;   // 0..16383
        int jj = idx & 7, l = (idx >> 3) & 63, t = idx >> 9;
        {
            int nt = t & 1, gks = t >> 1;
            int f = nt * 32 + (l & 31);
            int k = gks * 16 + (l >> 5) * 8 + jj;
            unsigned short hi, lo;
            splitbf(W1[f * F_IN + k], hi, lo);
            w1fh[idx] = hi; w1fl[idx] = lo;
        }
        if (idx < 4096) {
            int nt = t & 1, ks = t >> 1;   // t 0..7
            int f = nt * 32 + (l & 31);
            int j = ks * 16 + (l >> 5) * 8 + jj;
            unsigned short hi, lo;
            splitbf(W2[f * F_OUT + j], hi, lo);
            w2fh[idx] = hi; w2fl[idx] = lo;
        }
        return;
    }

    // ---- scatter half ----
    const int bid = blockIdx.x - 16;
    if (tid < 256) lh[tid] = 0;
    __syncthreads();
    const int beg = bid * chunk;
    const int end = min(E, beg + chunk);
    for (int i = beg + tid; i < end; i += 1024)
        atomicAdd(&lh[((unsigned)dst[i]) >> 8], 1);
    __syncthreads();
    if (tid < 256) {
        int c = lh[tid];
        lbase[tid] = c ? atomicAdd(&cursor[tid], c) : 0;
        lcur[tid] = 0;
    }
    __syncthreads();
    for (int i = beg + tid; i < end; i += 1024) {
        int d = dst[i];
        int s = src[i];
        int b = ((unsigned)d) >> 8;
        int rk = atomicAdd(&lcur[b], 1);
        edata[b * CAP + lbase[b] + rk] = ((d & 0xFF) << 16) | s;
    }
}

// ---------------------------------------------------------------------------
// L2: mlp (blocks 0..MLPB-1) UNION bucket_sort (blocks MLPB..MLPB+nbc-1).
//
// mlp (R12): coalesced x via PER-WAVE-PRIVATE LDS staging, barrier-free.
// R10 lesson: lane-per-row x loads expand to ~32 cache lines/instr ->
// latency-bound. R11 lesson: fixing that via a global pre-pass costs a
// 102MB HBM round-trip (+15us). Here: per K-half (128 feats), each wave
// does 16 coalesced float4 loads (2 rows/instr, 128B-contiguous), hi/lo
// split in registers, ds_write_b64 to a stride-134 (odd-dw, <=2-way
// conflict, R0-verified) private buffer, then 8 ksteps of ds_read_b128
// fragments + 6 MFMAs. Ordering is wave-internal vmcnt/lgkmcnt only.
// z transpose for GEMM2 aliases the same region (sequential in-wave).
//
// sort: fine counting sort within each coarse bucket (stride 256).
// ---------------------------------------------------------------------------
__global__ __launch_bounds__(256, 2)
void mlp_sort_kernel(const float* __restrict__ x,
                     const unsigned short* __restrict__ w1fh,
                     const unsigned short* __restrict__ w1fl,
                     const unsigned short* __restrict__ w2fh,
                     const unsigned short* __restrict__ w2fl,
                     const float* __restrict__ a,
                     unsigned short* __restrict__ hb,
                     float* __restrict__ sdst,
                     float* __restrict__ ssrc, int N,
                     const int* __restrict__ cursor,
                     const int* __restrict__ edata,
                     int* __restrict__ ssorted,
                     int* __restrict__ cnt, int* __restrict__ offs,
                     int MLPB)
{
    // per-wave region: 8576 ushorts (17152B). x-stage: xh[32][134] at +0,
    // xl[32][134] at +4288. GEMM2 z: zh[32][66] at +0, zl at +2112 (alias,
    // used after GEMM1 reads complete; wave-sequential -> safe).
    __shared__ __align__(16) unsigned short zbuf[4 * 8576];
    __shared__ int hist[256];
    __shared__ int excl[256];

    const int tid = threadIdx.x;
    const int lane = tid & 63;

    if (blockIdx.x < MLPB) {   // ---- mlp half ----
        const int wid = __builtin_amdgcn_readfirstlane(tid >> 6);
        const int ml = lane & 31;          // node index within wave tile
        const int q = lane >> 5;           // K-octet selector
        const int hl = lane >> 5;          // row parity for staging loads
        const int cl = lane & 31;          // col group for staging loads
        const int node0w = blockIdx.x * 128 + wid * 32;

        unsigned short* xh = zbuf + wid * 8576;
        unsigned short* xl = xh + 4288;
        unsigned short* zh = xh;           // aliases (sequential use)
        unsigned short* zl = xh + 2112;

        f32x16 acc0, acc1;
#pragma unroll
        for (int i = 0; i < 16; i++) { acc0[i] = 0.f; acc1[i] = 0.f; }

        // ---- GEMM1: z = relu(x @ W1^T), K=256 as 2 halves x 8 ksteps ----
#pragma unroll
        for (int half = 0; half < 2; half++) {
            float4 v[16];
#pragma unroll
            for (int i = 0; i < 16; i++) {
                int r = 2 * i + hl;
                int rr = min(node0w + r, N - 1);
                v[i] = *(const float4*)(x + (size_t)rr * F_IN + half * 128 + cl * 4);
            }
#pragma unroll
            for (int i = 0; i < 16; i++) {
                int r = 2 * i + hl;
                ushort4 h4, l4;
                unsigned short th, tl;
                splitbf(v[i].x, th, tl); h4.x = th; l4.x = tl;
                splitbf(v[i].y, th, tl); h4.y = th; l4.y = tl;
                splitbf(v[i].z, th, tl); h4.z = th; l4.z = tl;
                splitbf(v[i].w, th, tl); h4.w = th; l4.w = tl;
                *(ushort4*)(xh + r * 134 + cl * 4) = h4;
                *(ushort4*)(xl + r * 134 + cl * 4) = l4;
            }
#pragma unroll
            for (int ks = 0; ks < 8; ks++) {
                int gks = half * 8 + ks;
                bf16x8 ah = asbf8(*(const ushort8_t*)(xh + ml * 134 + ks * 16 + q * 8));
                bf16x8 al = asbf8(*(const ushort8_t*)(xl + ml * 134 + ks * 16 + q * 8));
                bf16x8 bh0 = asbf8(*(const ushort8_t*)(w1fh + ((gks * 2 + 0) * 64 + lane) * 8));
                bf16x8 bl0 = asbf8(*(const ushort8_t*)(w1fl + ((gks * 2 + 0) * 64 + lane) * 8));
                bf16x8 bh1 = asbf8(*(const ushort8_t*)(w1fh + ((gks * 2 + 1) * 64 + lane) * 8));
                bf16x8 bl1 = asbf8(*(const ushort8_t*)(w1fl + ((gks * 2 + 1) * 64 + lane) * 8));
                acc0 = __builtin_amdgcn_mfma_f32_32x32x16_bf16(ah, bh0, acc0, 0, 0, 0);
                acc0 = __builtin_amdgcn_mfma_f32_32x32x16_bf16(ah, bl0, acc0, 0, 0, 0);
                acc0 = __builtin_amdgcn_mfma_f32_32x32x16_bf16(al, bh0, acc0, 0, 0, 0);
                acc1 = __builtin_amdgcn_mfma_f32_32x32x16_bf16(ah, bh1, acc1, 0, 0, 0);
                acc1 = __builtin_amdgcn_mfma_f32_32x32x16_bf16(ah, bl1, acc1, 0, 0, 0);
                acc1 = __builtin_amdgcn_mfma_f32_32x32x16_bf16(al, bh1, acc1, 0, 0, 0);
            }
        }

        // ---- z -> per-wave LDS (hi/lo), C layout: col(feat)=lane&31,
        // row(node) = (reg&3)+8*(reg>>2)+4*q ----
#pragma unroll
        for (int reg = 0; reg < 16; reg++) {
            int nd = (reg & 3) + 8 * (reg >> 2) + 4 * q;
            float z0 = fmaxf(acc0[reg], 0.f);
            float z1 = fmaxf(acc1[reg], 0.f);
            unsigned short h_, l_;
            splitbf(z0, h_, l_);
            zh[nd * 66 + ml] = h_; zl[nd * 66 + ml] = l_;
            splitbf(z1, h_, l_);
            zh[nd * 66 + 32 + ml] = h_; zl[nd * 66 + 32 + ml] = l_;
        }
        // wave-private region: lgkmcnt orders the dependent ds_read.

        // ---- GEMM2: h = relu(z @ W2^T), K=64 as 4 MFMA k-steps ----
        f32x16 hacc0, hacc1;
#pragma unroll
        for (int i = 0; i < 16; i++) { hacc0[i] = 0.f; hacc1[i] = 0.f; }
#pragma unroll
        for (int ks = 0; ks < 4; ks++) {
            bf16x8 wh0 = asbf8(*(const ushort8_t*)(w2fh + ((ks * 2 + 0) * 64 + lane) * 8));
            bf16x8 wl0 = asbf8(*(const ushort8_t*)(w2fl + ((ks * 2 + 0) * 64 + lane) * 8));
            bf16x8 wh1 = asbf8(*(const ushort8_t*)(w2fh + ((ks * 2 + 1) * 64 + lane) * 8));
            bf16x8 wl1 = asbf8(*(const ushort8_t*)(w2fl + ((ks * 2 + 1) * 64 + lane) * 8));
            bf16x8 ah = asbf8(*(const ushort8_t*)(zh + ml * 66 + ks * 16 + q * 8));
            bf16x8 al = asbf8(*(const ushort8_t*)(zl + ml * 66 + ks * 16 + q * 8));
            hacc0 = __builtin_amdgcn_mfma_f32_32x32x16_bf16(ah, wh0, hacc0, 0, 0, 0);
            hacc0 = __builtin_amdgcn_mfma_f32_32x32x16_bf16(ah, wl0, hacc0, 0, 0, 0);
            hacc0 = __builtin_amdgcn_mfma_f32_32x32x16_bf16(al, wh0, hacc0, 0, 0, 0);
            hacc1 = __builtin_amdgcn_mfma_f32_32x32x16_bf16(ah, wh1, hacc1, 0, 0, 0);
            hacc1 = __builtin_amdgcn_mfma_f32_32x32x16_bf16(ah, wl1, hacc1, 0, 0, 0);
            hacc1 = __builtin_amdgcn_mfma_f32_32x32x16_bf16(al, wh1, hacc1, 0, 0, 0);
        }

        // ---- epilogue: scores via in-register xor-tree, hb from regs ----
        const float aD0 = a[ml],            aD1 = a[32 + ml];
        const float aS0 = a[F_OUT + ml],    aS1 = a[F_OUT + 32 + ml];

        float sdv = 0.f, ssv = 0.f;
#pragma unroll
        for (int reg = 0; reg < 16; reg++) {
            int nd = (reg & 3) + 8 * (reg >> 2) + 4 * q;
            float h0 = fmaxf(hacc0[reg], 0.f);
            float h1 = fmaxf(hacc1[reg], 0.f);
            float td = redq32(h0 * aD0 + h1 * aD1);
            float ts = redq32(h0 * aS0 + h1 * aS1);
            if (ml == nd) { sdv = td; ssv = ts; }
            int gn = node0w + nd;
            if (gn < N) {
                hb[(size_t)gn * F_OUT + ml]      = f2bf(h0);
                hb[(size_t)gn * F_OUT + 32 + ml] = f2bf(h1);
            }
        }
        {
            int gn = node0w + ml;
            if ((((ml >> 2) & 1) == q) && gn < N) {
                sdst[gn] = sdv;
                ssrc[gn] = ssv;
            }
        }
        return;
    }

    // ---- sort half ----
    const int cb = blockIdx.x - MLPB;
    const int base = cb * CAP;
    const int ecnt = cursor[cb];

    hist[tid] = 0;
    __syncthreads();
    for (int i = tid; i < ecnt; i += 256)
        atomicAdd(&hist[((unsigned)edata[base + i]) >> 16], 1);
    __syncthreads();

    if (tid < 64) {
        int v0 = hist[lane * 4], v1 = hist[lane * 4 + 1];
        int v2 = hist[lane * 4 + 2], v3 = hist[lane * 4 + 3];
        int ts = v0 + v1 + v2 + v3;
        int s = ts;
#pragma unroll
        for (int d = 1; d < 64; d <<= 1) {
            int t = __shfl_up(s, d);
            if (lane >= d) s += t;
        }
        int e = s - ts;
        excl[lane * 4] = e;
        excl[lane * 4 + 1] = e + v0;
        excl[lane * 4 + 2] = e + v0 + v1;
        excl[lane * 4 + 3] = e + v0 + v1 + v2;
    }
    __syncthreads();

    {
        int d = cb * 256 + tid;
        if (d < N) {
            cnt[d] = hist[tid];
            offs[d] = base + excl[tid];
        }
    }
    __syncthreads();

    for (int i = tid; i < ecnt; i += 256) {
        int pack = edata[base + i];
        int low = ((unsigned)pack) >> 16;
        int rk = atomicAdd(&excl[low], 1);
        ssorted[base + rk] = pack & 0xFFFF;
    }
}

// ---------------------------------------------------------------------------
// L3: per-dst-node online-softmax aggregation (R10 structure: 4 nodes per
// wave, 16-lane groups; ushort4 row gathers; float4 output).
// ---------------------------------------------------------------------------
__global__ __launch_bounds__(256)
void aggregate_kernel(const unsigned short* __restrict__ hb,
                      const float* __restrict__ sdst,
                      const float* __restrict__ ssrc,
                      const int* __restrict__ offs,
                      const int* __restrict__ cnt,
                      const int* __restrict__ ssorted,
                      float* __restrict__ out, int N)
{
    __shared__ float2 ws_sh[4][64];
    const int tid = threadIdx.x;
    const int lane = tid & 63;
    const int wid = tid >> 6;
    const int g = lane >> 4;          // node group within wave (0..3)
    const int li = lane & 15;         // lane within group
    const int d = blockIdx.x * 16 + wid * 4 + g;
    const bool vd = d < N;

    const int off = vd ? offs[d] : 0;
    const int deg = vd ? cnt[d] : 0;
    const float sdd = vd ? sdst[d] : 0.f;

    float M = -INFINITY, S = 0.f;
    float c0 = 0.f, c1 = 0.f, c2 = 0.f, c3 = 0.f;

    for (int cb = 0; cb < deg; cb += 16) {
        int ce = min(16, deg - cb);
        float score = -INFINITY;
        int s = 0;
        if (li < ce) {
            s = ssorted[off + cb + li];
            float sc = sdd + ssrc[s];
            score = sc > 0.f ? sc : NEG_SLOPE * sc;
        }
        float mc = score;
        mc = fmaxf(mc, __shfl_xor(mc, 1));
        mc = fmaxf(mc, __shfl_xor(mc, 2));
        mc = fmaxf(mc, __shfl_xor(mc, 4));
        mc = fmaxf(mc, __shfl_xor(mc, 8));
        float newM = fmaxf(M, mc);
        float scale = __expf(M - newM);
        float w = (li < ce) ? __expf(score - newM) : 0.f;
        ws_sh[wid][lane] = make_float2(w, __int_as_float(s));
        float csum = w;
        csum += __shfl_xor(csum, 1);
        csum += __shfl_xor(csum, 2);
        csum += __shfl_xor(csum, 4);
        csum += __shfl_xor(csum, 8);
        S = S * scale + csum;
        __builtin_amdgcn_wave_barrier();

        // gather: 16 edges (zero-weight padded), lane li covers feats 4li..4li+3
        float t0 = 0.f, t1 = 0.f, t2 = 0.f, t3 = 0.f;
#pragma unroll
        for (int e = 0; e < 16; e++) {
            float2 tw = ws_sh[wid][g * 16 + e];
            int se = __float_as_int(tw.y);
            ushort4 r = *(const ushort4*)(hb + (((size_t)(unsigned)se) << 6) + li * 4);
            t0 = fmaf(tw.x, bf2f(r.x), t0);
            t1 = fmaf(tw.x, bf2f(r.y), t1);
            t2 = fmaf(tw.x, bf2f(r.z), t2);
            t3 = fmaf(tw.x, bf2f(r.w), t3);
        }
        c0 = c0 * scale + t0;
        c1 = c1 * scale + t1;
        c2 = c2 * scale + t2;
        c3 = c3 * scale + t3;
        __builtin_amdgcn_wave_barrier();
        M = newM;
    }

    if (vd) {
        ushort4 hr = *(const ushort4*)(hb + (((size_t)(unsigned)d) << 6) + li * 4);
        float inv = (S > 0.f) ? 1.f / S : 0.f;
        float r0 = bf2f(hr.x) - c0 * inv;
        float r1 = bf2f(hr.y) - c1 * inv;
        float r2 = bf2f(hr.z) - c2 * inv;
        float r3 = bf2f(hr.w) - c3 * inv;
        float4 o;
        o.x = r0 > 0.f ? r0 : 0.f;
        o.y = r1 > 0.f ? r1 : 0.f;
        o.z = r2 > 0.f ? r2 : 0.f;
        o.w = r3 > 0.f ? r3 : 0.f;
        *(float4*)(out + (size_t)d * F_OUT + li * 4) = o;
    }
}

// ---------------------------------------------------------------------------
extern "C" void kernel_launch(void* const* d_in, const int* in_sizes, int n_in,
                              void* d_out, int out_size, void* d_ws,
                              size_t ws_size, hipStream_t stream)
{
    const float* x  = (const float*)d_in[0];
    const float* W1 = (const float*)d_in[1];
    const float* W2 = (const float*)d_in[2];
    const float* a  = (const float*)d_in[3];
    const int* src  = (const int*)d_in[4];
    const int* dst  = (const int*)d_in[5];
    const int N = in_sizes[0] / F_IN;   // 50000
    const int E = in_sizes[4];          // 800000

    float* ws = (float*)d_ws;
    float* sdst = ws;                                   // N
    float* ssrc = sdst + N;                             // N
    unsigned short* w1fh = (unsigned short*)(ssrc + N); // 16384 us
    unsigned short* w1fl = w1fh + 16384;                // 16384 us
    unsigned short* w2fh = w1fl + 16384;                // 4096 us
    unsigned short* w2fl = w2fh + 4096;                 // 4096 us
    unsigned short* hb = w2fl + 4096;                   // N*64 us
    int* cnt    = (int*)(hb + (size_t)N * F_OUT);       // N
    int* offs   = cnt + N;                              // N
    int* cursor = offs + N;                             // 256
    int* edata  = cursor + 256;                         // 196*CAP
    int* ssorted = edata + 196 * CAP;                   // 196*CAP

    const int nbc = (N + 255) >> 8;                     // 196
    const int MLPB = (N + 127) >> 7;                    // 391
    const int chunk = (E + NB2 - 1) / NB2;

    hipMemsetAsync(cursor, 0, 256 * sizeof(int), stream);
    prep_scatter_kernel<<<16 + NB2, 1024, 0, stream>>>(W1, W2, w1fh, w1fl, w2fh, w2fl,
                                                       src, dst, cursor, edata, E, chunk);
    mlp_sort_kernel<<<MLPB + nbc, 256, 0, stream>>>(x, w1fh, w1fl, w2fh, w2fl, a,
                                                    hb, sdst, ssrc, N,
                                                    cursor, edata, ssorted, cnt, offs,
                                                    MLPB);
    aggregate_kernel<<<(N + 15) / 16, 256, 0, stream>>>(hb, sdst, ssrc, offs, cnt,
                                                        ssorted, (float*)d_out, N);
}